// Round 1
// baseline (11972.794 us; speedup 1.0000x reference)
//
#include <hip/hip_runtime.h>

#define T_SEQ 512
#define HID   512
#define IND   128
#define GN    32          // WGs per M-group (N-partition)
#define NT    16          // h-cols per WG

typedef __attribute__((ext_vector_type(8))) short short8;
typedef __attribute__((ext_vector_type(4))) float f32x4;
typedef __attribute__((ext_vector_type(4))) int   i32x4;

static __device__ __forceinline__ unsigned short f2bf(float x) {
  unsigned u = __builtin_bit_cast(unsigned, x);
  u = (u + 0x7fffu + ((u >> 16) & 1u)) >> 16;   // RNE
  return (unsigned short)u;
}
static __device__ __forceinline__ float bf2f(unsigned short s) {
  unsigned u = ((unsigned)s) << 16;
  return __builtin_bit_cast(float, u);
}
static __device__ __forceinline__ float sigf(float x) {
  return 1.0f / (1.0f + __expf(-x));
}
static __device__ __forceinline__ float tanhfast(float x) {
  // 1 - 2/(e^{2x}+1): saturates cleanly to +-1, no inf/inf
  float e = __expf(2.0f * x);
  return 1.0f - 2.0f / (e + 1.0f);
}

__global__ __launch_bounds__(256, 1)
void lstm_persist(const float* __restrict__ x,
                  const float* __restrict__ w_ih,
                  const float* __restrict__ w_hh,
                  const float* __restrict__ b_ih,
                  const float* __restrict__ b_hh,
                  const float* __restrict__ w_lin,
                  const float* __restrict__ b_lin,
                  float* __restrict__ out,
                  unsigned char* __restrict__ ws)
{
  // LDS: [0,64K) w_hh slice (64 gate-rows x 512 k, bf16, XOR-swizzled)
  //      [64K,80K) w_ih slice (64 gate-rows x 128 k, bf16, XOR-swizzled)
  __shared__ unsigned char lds[65536 + 16384];

  const int tid  = threadIdx.x;
  const int wave = tid >> 6;
  const int lane = tid & 63;
  const int l15  = lane & 15;
  const int lq   = lane >> 4;

  const int bid = blockIdx.x;      // 128 WGs
  const int mi  = bid >> 5;        // 0..3   (M-group, 64 batch rows)
  const int ni  = bid & 31;        // 0..31  (N-slice, 16 h-cols)
  const int m0  = mi * 64;
  const int mw  = m0 + wave * 16;  // wave's first batch row
  const int n0  = ni * NT;         // h-col base

  // ---- stage w_hh slice: global fp32 [2048][512] -> bf16 LDS, swizzled ----
  // slice row r = g*16 + j  <->  global gate row  g*512 + n0 + j
  for (int it = 0; it < 16; ++it) {
    int idx  = it * 256 + tid;        // 0..4095
    int r    = idx >> 6;              // 0..63
    int c8   = idx & 63;              // chunk of 8 fp32
    int grow = (r >> 4) * HID + n0 + (r & 15);
    const float* gp = w_hh + (size_t)grow * HID + c8 * 8;
    f32x4 a = *(const f32x4*)gp;
    f32x4 b = *(const f32x4*)(gp + 4);
    short8 s;
    s[0] = (short)f2bf(a[0]); s[1] = (short)f2bf(a[1]);
    s[2] = (short)f2bf(a[2]); s[3] = (short)f2bf(a[3]);
    s[4] = (short)f2bf(b[0]); s[5] = (short)f2bf(b[1]);
    s[6] = (short)f2bf(b[2]); s[7] = (short)f2bf(b[3]);
    int off = r * 1024 + ((c8 * 16) ^ ((r & 7) << 4));
    *(short8*)(lds + off) = s;
  }
  // ---- stage w_ih slice: global fp32 [2048][128] -> bf16 LDS, swizzled ----
  for (int it = 0; it < 4; ++it) {
    int idx  = it * 256 + tid;        // 0..1023
    int r    = idx >> 4;              // 0..63
    int c8   = idx & 15;
    int grow = (r >> 4) * HID + n0 + (r & 15);
    const float* gp = w_ih + (size_t)grow * IND + c8 * 8;
    f32x4 a = *(const f32x4*)gp;
    f32x4 b = *(const f32x4*)(gp + 4);
    short8 s;
    s[0] = (short)f2bf(a[0]); s[1] = (short)f2bf(a[1]);
    s[2] = (short)f2bf(a[2]); s[3] = (short)f2bf(a[3]);
    s[4] = (short)f2bf(b[0]); s[5] = (short)f2bf(b[1]);
    s[6] = (short)f2bf(b[2]); s[7] = (short)f2bf(b[3]);
    int off = 65536 + r * 256 + ((c8 * 16) ^ ((r & 7) << 4));
    *(short8*)(lds + off) = s;
  }
  __syncthreads();

  // ---- gather w_hh B-fragments into registers (loop-invariant, 256 VGPR) ----
  // B-frag for (gate g, kstep ks): lane holds W[g*512+n0+l15][ks*32+lq*8 .. +8]
  short8 wf[64];
#pragma unroll
  for (int g = 0; g < 4; ++g) {
#pragma unroll
    for (int ks = 0; ks < 16; ++ks) {
      int r   = g * 16 + l15;
      int off = r * 1024 + (((ks * 64) + lq * 16) ^ ((r & 7) << 4));
      wf[g * 16 + ks] = *(const short8*)(lds + off);
    }
  }

  // bias per gate for this lane's column
  float biasv[4];
#pragma unroll
  for (int g = 0; g < 4; ++g) {
    int gc = g * HID + n0 + l15;
    biasv[g] = b_ih[gc] + b_hh[gc];
  }

  // barrier state (per M-group), zeroed by host memset each call
  unsigned* cnt = (unsigned*)(ws + 524288 + (size_t)mi * 256);
  unsigned* gen = (unsigned*)(ws + 524288 + (size_t)mi * 256 + 128);

  // per-lane x base (bytes): row = mw + l15, chunk lq*8 fp32
  const unsigned char* xbase = (const unsigned char*)x
      + (size_t)(mw + l15) * T_SEQ * IND * 4 + (size_t)lq * 32;

  // per-lane byte offset inside an h buffer: row-major [256][512] bf16
  const int hoff = ((mw + l15) * HID + lq * 8) * 2;

  f32x4 cacc = {0.f, 0.f, 0.f, 0.f};   // cell state frag (16 rows x 16 cols / wave)

  int p = 0;
  for (int t = 0; t < T_SEQ; ++t) {
    // ---- issue h A-fragment loads (global, deep latency first) ----
    const unsigned char* hb = ws + (size_t)p * 262144 + hoff;
    short8 ha[16];
#pragma unroll
    for (int ks = 0; ks < 16; ++ks)
      ha[ks] = *(const short8*)(hb + ks * 64);

    // ---- x A-fragments: load fp32, convert to bf16 ----
    const float* xp = (const float*)(xbase + (size_t)t * IND * 4);
    short8 xa[4];
#pragma unroll
    for (int ks = 0; ks < 4; ++ks) {
      f32x4 a = *(const f32x4*)(xp + ks * 32);
      f32x4 b = *(const f32x4*)(xp + ks * 32 + 4);
      short8 s;
      s[0] = (short)f2bf(a[0]); s[1] = (short)f2bf(a[1]);
      s[2] = (short)f2bf(a[2]); s[3] = (short)f2bf(a[3]);
      s[4] = (short)f2bf(b[0]); s[5] = (short)f2bf(b[1]);
      s[6] = (short)f2bf(b[2]); s[7] = (short)f2bf(b[3]);
      xa[ks] = s;
    }

    // ---- accumulators = bias ----
    f32x4 acc[4];
#pragma unroll
    for (int g = 0; g < 4; ++g) {
      f32x4 v = {biasv[g], biasv[g], biasv[g], biasv[g]};
      acc[g] = v;
    }

    // ---- input projection MFMAs (B from LDS) ----
#pragma unroll
    for (int ks = 0; ks < 4; ++ks) {
#pragma unroll
      for (int g = 0; g < 4; ++g) {
        int r   = g * 16 + l15;
        int off = 65536 + r * 256 + (((ks * 64) + lq * 16) ^ ((r & 7) << 4));
        short8 bfr = *(const short8*)(lds + off);
        acc[g] = __builtin_amdgcn_mfma_f32_16x16x32_bf16(xa[ks], bfr, acc[g], 0, 0, 0);
      }
    }

    // ---- hidden MFMAs (B from registers) ----
#pragma unroll
    for (int ks = 0; ks < 16; ++ks) {
#pragma unroll
      for (int g = 0; g < 4; ++g)
        acc[g] = __builtin_amdgcn_mfma_f32_16x16x32_bf16(ha[ks], wf[g * 16 + ks], acc[g], 0, 0, 0);
    }

    // ---- pointwise LSTM cell (fragment-local; C/D layout: col=l15, row=lq*4+r) ----
    unsigned char* hn = ws + (size_t)(p ^ 1) * 262144;
    unsigned short hs[4];
#pragma unroll
    for (int r = 0; r < 4; ++r) {
      float iv = sigf(acc[0][r]);
      float fv = sigf(acc[1][r]);
      float gv = tanhfast(acc[2][r]);
      float ov = sigf(acc[3][r]);
      float cn = fv * cacc[r] + iv * gv;
      cacc[r] = cn;
      hs[r] = f2bf(ov * tanhfast(cn));
    }
#pragma unroll
    for (int r = 0; r < 4; ++r) {
      int row = mw + lq * 4 + r;
      *(unsigned short*)(hn + ((size_t)row * HID + n0 + l15) * 2) = hs[r];
    }

    // ---- group barrier (32 WGs sharing this M-group) ----
    __syncthreads();                    // drains this WG's h stores (vmcnt 0)
    if (tid == 0) {
      __threadfence();                  // agent release: L2 writeback to LLC
      unsigned a = __hip_atomic_fetch_add(cnt, 1u, __ATOMIC_ACQ_REL, __HIP_MEMORY_SCOPE_AGENT);
      if (a == GN - 1) {
        __hip_atomic_store(cnt, 0u, __ATOMIC_RELAXED, __HIP_MEMORY_SCOPE_AGENT);
        __hip_atomic_fetch_add(gen, 1u, __ATOMIC_RELEASE, __HIP_MEMORY_SCOPE_AGENT);
      } else {
        while (__hip_atomic_load(gen, __ATOMIC_ACQUIRE, __HIP_MEMORY_SCOPE_AGENT)
               < (unsigned)(t + 1)) {
          __builtin_amdgcn_s_sleep(2);
        }
      }
    }
    __syncthreads();
    __threadfence();                    // agent acquire: invalidate stale cache lines
    p ^= 1;
  }

  // ---- final linear: out[256] = h_last @ w_lin^T + b_lin (h_last in buf0) ----
  if (ni == 0) {
    const unsigned short* hb = (const unsigned short*)ws;  // buffer 0
    float bl = b_lin[0];
    f32x4 w0 = *(const f32x4*)(w_lin + lane * 8);
    f32x4 w1 = *(const f32x4*)(w_lin + lane * 8 + 4);
#pragma unroll 1
    for (int r = 0; r < 16; ++r) {
      int row = mw + r;
      i32x4 hv = *(const i32x4*)(hb + (size_t)row * HID + lane * 8);
      float s = 0.f;
#pragma unroll
      for (int w = 0; w < 4; ++w) {
        unsigned v = (unsigned)hv[w];
        float lo = bf2f((unsigned short)(v & 0xffffu));
        float hi = bf2f((unsigned short)(v >> 16));
        float wa = (w < 2) ? ((w == 0) ? w0[0] : w0[2]) : ((w == 2) ? w1[0] : w1[2]);
        float wb = (w < 2) ? ((w == 0) ? w0[1] : w0[3]) : ((w == 2) ? w1[1] : w1[3]);
        s += lo * wa + hi * wb;
      }
#pragma unroll
      for (int off = 32; off >= 1; off >>= 1)
        s += __shfl_xor(s, off, 64);
      if (lane == 0) out[row] = s + bl;
    }
  }
}

extern "C" void kernel_launch(void* const* d_in, const int* in_sizes, int n_in,
                              void* d_out, int out_size, void* d_ws, size_t ws_size,
                              hipStream_t stream)
{
  const float* x     = (const float*)d_in[0];
  const float* w_ih  = (const float*)d_in[1];
  const float* w_hh  = (const float*)d_in[2];
  const float* b_ih  = (const float*)d_in[3];
  const float* b_hh  = (const float*)d_in[4];
  const float* w_lin = (const float*)d_in[5];
  const float* b_lin = (const float*)d_in[6];

  // ws layout: [0,256K) h buf0 | [256K,512K) h buf1 | [512K,+2K) barrier counters
  hipMemsetAsync(d_ws, 0, 524288 + 2048, stream);
  hipLaunchKernelGGL(lstm_persist, dim3(128), dim3(256), 0, stream,
                     x, w_ih, w_hh, b_ih, b_hh, w_lin, b_lin,
                     (float*)d_out, (unsigned char*)d_ws);
}

// Round 3
// 4083.550 us; speedup vs baseline: 2.9320x; 2.9320x over previous
//
#include <hip/hip_runtime.h>

#define T_SEQ 512
#define HID   512
#define IND   128
#define GN    32          // WGs per M-group (N-partition)
#define NT    16          // h-cols per WG

typedef __attribute__((ext_vector_type(8))) short short8;
typedef __attribute__((ext_vector_type(4))) float f32x4;
typedef __attribute__((ext_vector_type(2))) unsigned long long ull2;

static __device__ __forceinline__ unsigned short f2bf(float x) {
  unsigned u = __builtin_bit_cast(unsigned, x);
  u = (u + 0x7fffu + ((u >> 16) & 1u)) >> 16;   // RNE
  return (unsigned short)u;
}
static __device__ __forceinline__ float bf2f(unsigned short s) {
  unsigned u = ((unsigned)s) << 16;
  return __builtin_bit_cast(float, u);
}
static __device__ __forceinline__ float sigf(float x) {
  return 1.0f / (1.0f + __expf(-x));
}
static __device__ __forceinline__ float tanhfast(float x) {
  float e = __expf(2.0f * x);   // saturates cleanly, no inf/inf
  return 1.0f - 2.0f / (e + 1.0f);
}

__global__ __launch_bounds__(256, 1)
void lstm_persist(const float* __restrict__ x,
                  const float* __restrict__ w_ih,
                  const float* __restrict__ w_hh,
                  const float* __restrict__ b_ih,
                  const float* __restrict__ b_hh,
                  const float* __restrict__ w_lin,
                  const float* __restrict__ b_lin,
                  float* __restrict__ out,
                  unsigned char* __restrict__ ws)
{
  // LDS: [0,64K) w_hh slice (64 gate-rows x 512 k, bf16, XOR-swizzled)
  //      [64K,80K) w_ih slice (64 gate-rows x 128 k, bf16, XOR-swizzled)
  __shared__ unsigned char lds[65536 + 16384];

  const int tid  = threadIdx.x;
  const int wave = tid >> 6;
  const int lane = tid & 63;
  const int l15  = lane & 15;
  const int lq   = lane >> 4;

  const int bid = blockIdx.x;      // 128 WGs
  const int mi  = bid >> 5;        // 0..3   (M-group, 64 batch rows)
  const int ni  = bid & 31;        // 0..31  (N-slice, 16 h-cols)
  const int m0  = mi * 64;
  const int mw  = m0 + wave * 16;  // wave's first batch row
  const int n0  = ni * NT;         // h-col base

  // ---- stage w_hh slice: global fp32 [2048][512] -> bf16 LDS, swizzled ----
  for (int it = 0; it < 16; ++it) {
    int idx  = it * 256 + tid;        // 0..4095
    int r    = idx >> 6;              // 0..63
    int c8   = idx & 63;              // chunk of 8 fp32
    int grow = (r >> 4) * HID + n0 + (r & 15);
    const float* gp = w_hh + (size_t)grow * HID + c8 * 8;
    f32x4 a = *(const f32x4*)gp;
    f32x4 b = *(const f32x4*)(gp + 4);
    short8 s;
    s[0] = (short)f2bf(a[0]); s[1] = (short)f2bf(a[1]);
    s[2] = (short)f2bf(a[2]); s[3] = (short)f2bf(a[3]);
    s[4] = (short)f2bf(b[0]); s[5] = (short)f2bf(b[1]);
    s[6] = (short)f2bf(b[2]); s[7] = (short)f2bf(b[3]);
    int off = r * 1024 + ((c8 * 16) ^ ((r & 7) << 4));
    *(short8*)(lds + off) = s;
  }
  // ---- stage w_ih slice: global fp32 [2048][128] -> bf16 LDS, swizzled ----
  for (int it = 0; it < 4; ++it) {
    int idx  = it * 256 + tid;        // 0..1023
    int r    = idx >> 4;              // 0..63
    int c8   = idx & 15;
    int grow = (r >> 4) * HID + n0 + (r & 15);
    const float* gp = w_ih + (size_t)grow * IND + c8 * 8;
    f32x4 a = *(const f32x4*)gp;
    f32x4 b = *(const f32x4*)(gp + 4);
    short8 s;
    s[0] = (short)f2bf(a[0]); s[1] = (short)f2bf(a[1]);
    s[2] = (short)f2bf(a[2]); s[3] = (short)f2bf(a[3]);
    s[4] = (short)f2bf(b[0]); s[5] = (short)f2bf(b[1]);
    s[6] = (short)f2bf(b[2]); s[7] = (short)f2bf(b[3]);
    int off = 65536 + r * 256 + ((c8 * 16) ^ ((r & 7) << 4));
    *(short8*)(lds + off) = s;
  }
  __syncthreads();

  // ---- pin w_hh B-fragments in VGPRs: volatile loads (cannot rematerialize) ----
  short8 wf[64];
#pragma unroll
  for (int g = 0; g < 4; ++g) {
#pragma unroll
    for (int ks = 0; ks < 16; ++ks) {
      int r   = g * 16 + l15;
      int off = r * 1024 + (((ks * 64) + lq * 16) ^ ((r & 7) << 4));
      wf[g * 16 + ks] = *(const volatile short8*)(lds + off);
    }
  }

  // bias per gate for this lane's column
  float biasv[4];
#pragma unroll
  for (int g = 0; g < 4; ++g) {
    int gc = g * HID + n0 + l15;
    biasv[g] = b_ih[gc] + b_hh[gc];
  }

  // monotone barrier counter (per M-group), zeroed by host memset each call
  unsigned* cnt = (unsigned*)(ws + 524288 + (size_t)mi * 256);

  // per-lane x base (bytes): row = mw + l15, chunk lq*8 fp32
  const unsigned char* xbase = (const unsigned char*)x
      + (size_t)(mw + l15) * T_SEQ * IND * 4 + (size_t)lq * 32;

  // per-lane byte offset inside an h buffer: row-major [256][512] bf16
  const int hoff = ((mw + l15) * HID + lq * 8) * 2;

  f32x4 cacc = {0.f, 0.f, 0.f, 0.f};

  // ---- x-projection helper (B-frags from LDS; dst = bias + x_t @ w_ih^T) ----
  auto xproj = [&](int t, f32x4* dst) {
    const float* xp = (const float*)(xbase + (size_t)t * IND * 4);
    short8 xa[4];
#pragma unroll
    for (int ks = 0; ks < 4; ++ks) {
      f32x4 a = *(const f32x4*)(xp + ks * 32);
      f32x4 b = *(const f32x4*)(xp + ks * 32 + 4);
      short8 s;
      s[0] = (short)f2bf(a[0]); s[1] = (short)f2bf(a[1]);
      s[2] = (short)f2bf(a[2]); s[3] = (short)f2bf(a[3]);
      s[4] = (short)f2bf(b[0]); s[5] = (short)f2bf(b[1]);
      s[6] = (short)f2bf(b[2]); s[7] = (short)f2bf(b[3]);
      xa[ks] = s;
    }
#pragma unroll
    for (int g = 0; g < 4; ++g) {
      f32x4 v = {biasv[g], biasv[g], biasv[g], biasv[g]};
      dst[g] = v;
    }
#pragma unroll
    for (int ks = 0; ks < 4; ++ks) {
#pragma unroll
      for (int g = 0; g < 4; ++g) {
        int r   = g * 16 + l15;
        int off = 65536 + r * 256 + (((ks * 64) + lq * 16) ^ ((r & 7) << 4));
        short8 bfr = *(const short8*)(lds + off);
        dst[g] = __builtin_amdgcn_mfma_f32_16x16x32_bf16(xa[ks], bfr, dst[g], 0, 0, 0);
      }
    }
  };

  f32x4 xacc[4];
  xproj(0, xacc);

  int p = 0;
#pragma unroll 1
  for (int t = 0; t < T_SEQ; ++t) {
    short8 ha[16];
    if (t > 0) {
      if (tid == 0) {
        unsigned tgt = (unsigned)(GN * t);
        while (__hip_atomic_load(cnt, __ATOMIC_RELAXED, __HIP_MEMORY_SCOPE_AGENT) < tgt)
          __builtin_amdgcn_s_sleep(1);
      }
      __syncthreads();
      asm volatile("" ::: "memory");
      // coherent h loads (scope=agent -> serviced at LLC), hidden by xproj below
      const unsigned long long* hb =
          (const unsigned long long*)(ws + (size_t)p * 262144 + hoff);
#pragma unroll
      for (int ks = 0; ks < 16; ++ks) {
        ull2 q;
        q[0] = __hip_atomic_load(hb + ks * 8,     __ATOMIC_RELAXED, __HIP_MEMORY_SCOPE_AGENT);
        q[1] = __hip_atomic_load(hb + ks * 8 + 1, __ATOMIC_RELAXED, __HIP_MEMORY_SCOPE_AGENT);
        ha[ks] = __builtin_bit_cast(short8, q);
      }
    }

    // overlap h-load latency: x projection for t+1
    f32x4 xn[4];
    {
      int tn = (t + 1 < T_SEQ) ? t + 1 : T_SEQ - 1;
      xproj(tn, xn);
    }

    f32x4 acc[4];
#pragma unroll
    for (int g = 0; g < 4; ++g) acc[g] = xacc[g];

    if (t > 0) {
#pragma unroll
      for (int ks = 0; ks < 16; ++ks) {
#pragma unroll
        for (int g = 0; g < 4; ++g)
          acc[g] = __builtin_amdgcn_mfma_f32_16x16x32_bf16(ha[ks], wf[g * 16 + ks], acc[g], 0, 0, 0);
      }
    }

    // ---- pointwise LSTM cell (C/D layout: col=l15, row=lq*4+r) ----
    unsigned char* hn = ws + (size_t)(p ^ 1) * 262144;
    unsigned hsv[4];
#pragma unroll
    for (int r = 0; r < 4; ++r) {
      float iv = sigf(acc[0][r]);
      float fv = sigf(acc[1][r]);
      float gv = tanhfast(acc[2][r]);
      float ov = sigf(acc[3][r]);
      float cn = fv * cacc[r] + iv * gv;
      cacc[r] = cn;
      hsv[r] = (unsigned)f2bf(ov * tanhfast(cn));
    }
    // pack 4 cols -> 8B, store coherently from lanes with l15%4==0
#pragma unroll
    for (int r = 0; r < 4; ++r) {
      unsigned u0 = hsv[r];
      unsigned u1 = (unsigned)__shfl_xor((int)u0, 1, 64);
      unsigned v32 = (u0 & 0xffffu) | (u1 << 16);
      unsigned vhi = (unsigned)__shfl_xor((int)v32, 2, 64);
      unsigned long long v64 = (unsigned long long)v32 | ((unsigned long long)vhi << 32);
      if ((l15 & 3) == 0) {
        int row = mw + lq * 4 + r;
        unsigned long long* dst =
            (unsigned long long*)(hn + ((size_t)row * HID + n0 + l15) * 2);
        __hip_atomic_store(dst, v64, __ATOMIC_RELAXED, __HIP_MEMORY_SCOPE_AGENT);
      }
    }

    __syncthreads();   // drains vmcnt(0): h stores acked at coherence point
    if (tid == 0)
      __hip_atomic_fetch_add(cnt, 1u, __ATOMIC_RELAXED, __HIP_MEMORY_SCOPE_AGENT);

#pragma unroll
    for (int g = 0; g < 4; ++g) xacc[g] = xn[g];
    p ^= 1;
  }

  // ---- final linear: out[256] = h_last @ w_lin^T + b_lin (h_512 in buf0) ----
  if (ni == 0) {
    if (tid == 0) {
      while (__hip_atomic_load(cnt, __ATOMIC_RELAXED, __HIP_MEMORY_SCOPE_AGENT)
             < (unsigned)(GN * T_SEQ))
        __builtin_amdgcn_s_sleep(1);
    }
    __syncthreads();
    asm volatile("" ::: "memory");
    const unsigned long long* hb = (const unsigned long long*)ws;  // buffer 0
    float bl = b_lin[0];
    f32x4 w0 = *(const f32x4*)(w_lin + lane * 8);
    f32x4 w1 = *(const f32x4*)(w_lin + lane * 8 + 4);
#pragma unroll 1
    for (int r = 0; r < 16; ++r) {
      int row = mw + r;
      unsigned long long q0 = __hip_atomic_load(hb + (size_t)row * 128 + lane * 2,
                                                __ATOMIC_RELAXED, __HIP_MEMORY_SCOPE_AGENT);
      unsigned long long q1 = __hip_atomic_load(hb + (size_t)row * 128 + lane * 2 + 1,
                                                __ATOMIC_RELAXED, __HIP_MEMORY_SCOPE_AGENT);
      float s = 0.f;
      unsigned v;
      v = (unsigned)(q0 & 0xffffffffu);
      s += bf2f((unsigned short)(v & 0xffffu)) * w0[0] + bf2f((unsigned short)(v >> 16)) * w0[1];
      v = (unsigned)(q0 >> 32);
      s += bf2f((unsigned short)(v & 0xffffu)) * w0[2] + bf2f((unsigned short)(v >> 16)) * w0[3];
      v = (unsigned)(q1 & 0xffffffffu);
      s += bf2f((unsigned short)(v & 0xffffu)) * w1[0] + bf2f((unsigned short)(v >> 16)) * w1[1];
      v = (unsigned)(q1 >> 32);
      s += bf2f((unsigned short)(v & 0xffffu)) * w1[2] + bf2f((unsigned short)(v >> 16)) * w1[3];
#pragma unroll
      for (int off = 32; off >= 1; off >>= 1)
        s += __shfl_xor(s, off, 64);
      if (lane == 0) out[row] = s + bl;
    }
  }
}

extern "C" void kernel_launch(void* const* d_in, const int* in_sizes, int n_in,
                              void* d_out, int out_size, void* d_ws, size_t ws_size,
                              hipStream_t stream)
{
  const float* x     = (const float*)d_in[0];
  const float* w_ih  = (const float*)d_in[1];
  const float* w_hh  = (const float*)d_in[2];
  const float* b_ih  = (const float*)d_in[3];
  const float* b_hh  = (const float*)d_in[4];
  const float* w_lin = (const float*)d_in[5];
  const float* b_lin = (const float*)d_in[6];

  // ws layout: [0,256K) h buf0 | [256K,512K) h buf1 | [512K,+2K) barrier counters
  hipMemsetAsync((char*)d_ws + 524288, 0, 2048, stream);
  hipLaunchKernelGGL(lstm_persist, dim3(128), dim3(256), 0, stream,
                     x, w_ih, w_hh, b_ih, b_hh, w_lin, b_lin,
                     (float*)d_out, (unsigned char*)d_ws);
}